// Round 8
// baseline (498.467 us; speedup 1.0000x reference)
//
#include <hip/hip_runtime.h>
#include <math.h>

// Problem constants
static constexpr int H = 256, L = 141, N1 = 9, N2 = 34, N3 = 98;
static constexpr int B = 64, S = 512;

typedef __attribute__((ext_vector_type(8))) _Float16 f16x8;
typedef __attribute__((ext_vector_type(4))) float f32x4;

__device__ inline unsigned short f2h(float x) {
    _Float16 h = (_Float16)x;
    return __builtin_bit_cast(unsigned short, h);
}
__device__ inline float sigf(float x) { return 1.f / (1.f + __expf(-x)); }

__device__ inline void gload_lds16(const void* g, void* l) {
    __builtin_amdgcn_global_load_lds(
        (const __attribute__((address_space(1))) void*)g,
        (__attribute__((address_space(3))) void*)l, 16, 0, 0);
}

// ---------------------------------------------------------------------------
// MFMA fp16 GEMM. Tile = (32*IM) x 128, BK=64 (half the barriers of 32),
// 16x16x32_f16, 4 waves. A: [M][K] k-contig f16. B: [N][K] k-contig f16.
// XOR-8 swizzle: LDS row stride at BK=64 is 128B (one 4-bank window for all
// 16 l16 lanes of a ds_read_b128 -> 16-way conflict). Staging permutes the
// source 16B-unit per row (scol = (lane&7) ^ (lane>>3)); fragment reads use
// unit (sk*4+quad) ^ (l16&7). Row keys align since wm/wn/i*16 are mult of 8.
// A rows clamped to M-1, B rows clamped to N-1 (garbage guarded in epilogue).
// EPI 1: tanh(acc+bias[n]) -> outH[m][n] + LDS-transposed outHT (stride-72 T)
// EPI 2: pad-mask + fp32 C (bz=batch).  EPI 3: fp16 outH (bz=batch).
// EPI 4: K-split (bz = chunk of kChunk) -> fp32 partial slice C[bz][m][n].
// ---------------------------------------------------------------------------
template<int EPI, int IM, int BK>
__global__ __launch_bounds__(256) void gemm_mfma(
    const unsigned short* __restrict__ Ap, int lda, long strA,
    const unsigned short* __restrict__ Bp, int ldb, long strB,
    float* __restrict__ C, int ldc, long strC,
    int M, int N, int K,
    const float* __restrict__ bias,
    const int* __restrict__ tokens,
    unsigned short* __restrict__ outH,
    unsigned short* __restrict__ outHT,
    int kChunk)
{
    static_assert(BK == 64, "swizzle assumes BK==64");
    __shared__ unsigned short A_s[32 * IM * BK];
    __shared__ unsigned short B_s[128 * BK];
    __shared__ unsigned short T[EPI == 1 ? 128 * 72 : 1];  // [n_local][m_local]
    const int tid  = threadIdx.x;
    const int wave = tid >> 6, lane = tid & 63;
    const int quad = lane >> 4, l16 = lane & 15;
    const int srow = lane >> 3;                 // staging row within 8-row group
    const int scol = (lane & 7) ^ srow;         // swizzled 16B-unit in source
    const int bz = blockIdx.z;
    const int m0 = blockIdx.y * (32 * IM), n0 = blockIdx.x * 128;
    const int wm = (wave & 1) * (16 * IM), wn = (wave >> 1) * 64;

    long aBase, bBase;
    int kBeg, kEnd;
    if (EPI == 4) { aBase = 0; bBase = 0; kBeg = bz * kChunk; kEnd = kBeg + kChunk; }
    else { aBase = (long)bz * strA; bBase = (long)bz * strB; kBeg = 0; kEnd = K; }

    f32x4 acc[IM][4] = {};

    for (int k0 = kBeg; k0 < kEnd; k0 += BK) {
        // ---- stage A: 8 rows x 128B per gload round ----
        #pragma unroll
        for (int t = 0; t < IM; t++) {
            int rowb = wave * (8 * IM) + t * 8;
            int gm = m0 + rowb + srow; if (gm > M - 1) gm = M - 1;
            gload_lds16(Ap + aBase + (long)gm * lda + k0 + scol * 8,
                        &A_s[rowb * BK]);
        }
        // ---- stage B: 128 rows, 4 rounds of 8 rows per wave ----
        #pragma unroll
        for (int t = 0; t < 4; t++) {
            int rowb = wave * 32 + t * 8;
            int gn = n0 + rowb + srow; if (gn > N - 1) gn = N - 1;
            gload_lds16(Bp + bBase + (long)gn * ldb + k0 + scol * 8,
                        &B_s[rowb * BK]);
        }
        __syncthreads();
        const int key = l16 & 7;
        #pragma unroll
        for (int sk = 0; sk < BK / 32; sk++) {
            f16x8 a[IM], b[4];
            #pragma unroll
            for (int i = 0; i < IM; i++)
                a[i] = *(const f16x8*)&A_s[(wm + i * 16 + l16) * BK
                                           + (((sk << 2) + quad) ^ key) * 8];
            #pragma unroll
            for (int j = 0; j < 4; j++)
                b[j] = *(const f16x8*)&B_s[(wn + j * 16 + l16) * BK
                                           + (((sk << 2) + quad) ^ key) * 8];
            #pragma unroll
            for (int i = 0; i < IM; i++)
                #pragma unroll
                for (int j = 0; j < 4; j++)
                    acc[i][j] = __builtin_amdgcn_mfma_f32_16x16x32_f16(
                        a[i], b[j], acc[i][j], 0, 0, 0);
        }
        __syncthreads();
    }

    #pragma unroll
    for (int i = 0; i < IM; i++) {
        #pragma unroll
        for (int j = 0; j < 4; j++) {
            #pragma unroll
            for (int r = 0; r < 4; r++) {
                int ml = wm + i * 16 + quad * 4 + r;
                int nl = wn + j * 16 + l16;
                int gm = m0 + ml, gn = n0 + nl;
                if (gm >= M || gn >= N) continue;
                float v = acc[i][j][r];
                if (EPI == 1) {
                    v = tanhf(v + bias[gn]);
                    unsigned short hv = f2h(v);
                    outH[(long)gm * ldc + gn] = hv;
                    T[nl * 72 + ml] = hv;
                } else if (EPI == 2) {
                    int tok = tokens[(long)bz * 512 + gn];
                    if (tok == 0 || tok == 101 || tok == 102) v -= 1e30f;
                    C[(long)bz * strC + (long)gm * ldc + gn] = v;
                } else if (EPI == 3) {
                    outH[(long)bz * strC + (long)gm * ldc + gn] = f2h(v);
                } else { // EPI 4: partial K-slice
                    C[(long)bz * strC + (long)gm * ldc + gn] = v;
                }
            }
        }
    }
    if (EPI == 1) {
        // coalesced transposed write: 128 h-rows x 64 s (128B/lane)
        __syncthreads();
        int bb = m0 >> 9, s0 = m0 & 511;
        int rr = tid >> 1, half = tid & 1;
        const uint4* srcp = (const uint4*)&T[rr * 72 + half * 32];
        uint4* dstp = (uint4*)&outHT[((long)bb * 256 + n0 + rr) * 512 + s0 + half * 32];
        dstp[0] = srcp[0]; dstp[1] = srcp[1]; dstp[2] = srcp[2]; dstp[3] = srcp[3];
    }
}

// fp32 -> fp16 stream convert, 8 elems/thread
__global__ __launch_bounds__(256) void conv_h8(
    const float* __restrict__ src, unsigned short* __restrict__ dst, long n8)
{
    long i = (long)blockIdx.x * 256 + threadIdx.x;
    if (i >= n8) return;
    const float4* s = (const float4*)(src + i * 8);
    float4 v0 = s[0], v1 = s[1];
    unsigned int p0 = f2h(v0.x) | ((unsigned int)f2h(v0.y) << 16);
    unsigned int p1 = f2h(v0.z) | ((unsigned int)f2h(v0.w) << 16);
    unsigned int p2 = f2h(v1.x) | ((unsigned int)f2h(v1.y) << 16);
    unsigned int p3 = f2h(v1.z) | ((unsigned int)f2h(v1.w) << 16);
    *(uint4*)(dst + i * 8) = make_uint4(p0, p1, p2, p3);
}

// LDS-tiled transpose+convert: src fp32 [R][C] -> dst fp16 [C][R].
__global__ __launch_bounds__(256) void transp_t64(
    const float* __restrict__ src, unsigned short* __restrict__ dst,
    int R, int C)
{
    __shared__ unsigned short T[64 * 65];
    const int tid = threadIdx.x;
    const int r0 = blockIdx.x * 64, c0 = blockIdx.y * 64;
    #pragma unroll
    for (int p = 0; p < 16; p++) {
        int lin = p * 256 + tid;
        int r = lin >> 6, c = lin & 63;
        int gc = c0 + c;
        float v = (gc < C) ? src[(long)(r0 + r) * C + gc] : 0.f;
        T[c * 65 + r] = f2h(v);
    }
    __syncthreads();
    #pragma unroll
    for (int p = 0; p < 16; p++) {
        int lin = p * 256 + tid;
        int c = lin >> 6, r = lin & 63;
        if (c0 + c < C)
            dst[(long)(c0 + c) * R + r0 + r] = T[c * 65 + r];
    }
}

// gate_pre: G[j][m][n] = label_enc[m] @ W_j + b_j. grid (28, 141).
__global__ __launch_bounds__(256) void gate_pre(
    const float* __restrict__ le,
    const float* W0, const float* W1, const float* W2, const float* W3,
    const float* W4, const float* W5, const float* W6,
    const float* b0, const float* b1, const float* b2, const float* b3,
    const float* b4, const float* b5, const float* b6,
    float* __restrict__ G)
{
    __shared__ float ls[256];
    __shared__ float red[256];
    const int j = blockIdx.x >> 2, x = blockIdx.x & 3, m = blockIdx.y;
    const int tid = threadIdx.x, nl = tid & 63, ks = tid >> 6, n = x * 64 + nl;
    ls[tid] = le[(long)m * 256 + tid];
    __syncthreads();
    const float *W, *bb;
    switch (j) {
        case 0: W = W0; bb = b0; break;  case 1: W = W1; bb = b1; break;
        case 2: W = W2; bb = b2; break;  case 3: W = W3; bb = b3; break;
        case 4: W = W4; bb = b4; break;  case 5: W = W5; bb = b5; break;
        default: W = W6; bb = b6;
    }
    float a0 = 0, a1 = 0, a2 = 0, a3 = 0;
    for (int k = ks; k + 12 < 256; k += 16) {
        long o = (long)k * 256 + n;
        a0 += ls[k] * W[o];        a1 += ls[k + 4] * W[o + 1024];
        a2 += ls[k + 8] * W[o + 2048]; a3 += ls[k + 12] * W[o + 3072];
    }
    red[tid] = a0 + a1 + a2 + a3;
    __syncthreads();
    if (ks == 0)
        G[((long)j * 141 + m) * 256 + n] =
            red[nl] + red[64 + nl] + red[128 + nl] + red[192 + nl] + bb[n];
}

// pre2: independent two-stage row ops. grid (4, 273).
__global__ __launch_bounds__(256) void pre2(
    const float* __restrict__ A, const float* __restrict__ le,
    const float* __restrict__ w23, const float* __restrict__ w12,
    const float* __restrict__ Wp, const float* __restrict__ wf2_W,
    float* __restrict__ tmpP, float* __restrict__ wv2f, float* __restrict__ wv1f)
{
    __shared__ float cs[141];
    __shared__ float t[256];
    __shared__ float red[256];
    const int x = blockIdx.x, y = blockIdx.y;
    const int tid = threadIdx.x, nl = tid & 63, ks = tid >> 6, n = x * 64 + nl;
    int job, m, K1;
    if (y < 141)      { job = 0; m = y;       K1 = 141; }
    else if (y < 239) { job = 1; m = y - 141; K1 = 34; }
    else              { job = 2; m = y - 239; K1 = 9; }
    if (tid < K1)
        cs[tid] = (job == 0) ? A[(long)m * 141 + tid]
                : (job == 1) ? w23[(long)tid * 98 + m]
                             : w12[(long)tid * 34 + m];
    __syncthreads();
    const float* s1 = (job == 1) ? le + 9 * 256 : le;
    float acc = 0;
    #pragma unroll 4
    for (int k = 0; k < K1; k++) acc += cs[k] * s1[(long)k * 256 + tid];
    t[tid] = acc;
    __syncthreads();
    const float* W = (job == 0) ? Wp : wf2_W;
    float a0 = 0, a1 = 0, a2 = 0, a3 = 0;
    for (int k = ks; k + 12 < 256; k += 16) {
        long o = (long)k * 256 + n;
        a0 += t[k] * W[o];        a1 += t[k + 4] * W[o + 1024];
        a2 += t[k + 8] * W[o + 2048]; a3 += t[k + 12] * W[o + 3072];
    }
    red[tid] = a0 + a1 + a2 + a3;
    __syncthreads();
    if (ks == 0) {
        float tot = red[nl] + red[64 + nl] + red[128 + nl] + red[192 + nl];
        if (job == 0)      tmpP[(long)m * 256 + n] = fmaxf(tot, 0.f);
        else if (job == 1) wv2f[(long)m * 256 + n] = tot;
        else               wv1f[(long)m * 256 + n] = tot;
    }
}

// L1: elementwise gates -> h11,c11 (9r) and h32,c32 (98r). grid(107)
__global__ __launch_bounds__(256) void ew1(
    const float* __restrict__ G, float* __restrict__ h11, float* __restrict__ c11,
    float* __restrict__ h32, float* __restrict__ c32)
{
    int y = blockIdx.x, n = threadIdx.x;
    if (y < 9) {
        int m = y;
        float iv = sigf(G[(0L * 141 + m) * 256 + n]);
        float ov = sigf(G[(2L * 141 + m) * 256 + n]);
        float uv = tanhf(G[(3L * 141 + m) * 256 + n]);
        float cv = iv * uv;
        c11[m * 256 + n] = cv; h11[m * 256 + n] = ov * tanhf(cv);
    } else {
        int r = y - 9, grow = 43 + r;
        float iv = sigf(G[(4L * 141 + grow) * 256 + n]);
        float ov = sigf(G[(5L * 141 + grow) * 256 + n]);
        float uv = tanhf(G[(6L * 141 + grow) * 256 + n]);
        float cv = iv * uv;
        c32[r * 256 + n] = cv; h32[r * 256 + n] = ov * tanhf(cv);
    }
}

// chain_mm: fused sparse/row matmuls (see round-5 comments).
__global__ __launch_bounds__(256) void chain_mm(int phase,
    const float* __restrict__ w12, const float* __restrict__ w23,
    const float* __restrict__ fre23, const float* __restrict__ fre12,
    const float* __restrict__ h11, const float* __restrict__ c11,
    const float* __restrict__ h32,
    const float* __restrict__ h21, const float* __restrict__ c21,
    const float* __restrict__ h22,
    const float* __restrict__ wv2f, const float* __restrict__ wv1f,
    const float* __restrict__ wf2_b, const float* __restrict__ uf2_W,
    const float* __restrict__ c32, const float* __restrict__ c22,
    float* __restrict__ h21t, float* __restrict__ c21p,
    float* __restrict__ h22t, float* __restrict__ fcb,
    float* __restrict__ h31t, float* __restrict__ c31p,
    float* __restrict__ h12t, float* __restrict__ fc2b)
{
    __shared__ float cs[256];
    __shared__ float red[256];
    const int x = blockIdx.x, y = blockIdx.y;
    const int tid = threadIdx.x, nl = tid & 63, ks = tid >> 6, n = x * 64 + nl;
    int job, m;
    if (phase == 0) {
        if (y < 34)       { job = 0; m = y; }
        else if (y < 68)  { job = 1; m = y - 34; }
        else if (y < 102) { job = 2; m = y - 68; }
        else              { job = 3; m = y - 102; }
    } else {
        if (y < 98)       { job = 0; m = y; }
        else if (y < 196) { job = 1; m = y - 98; }
        else if (y < 205) { job = 2; m = y - 196; }
        else              { job = 3; m = y - 205; }
    }
    if (job < 3) {
        int K; const float* src; float* dst;
        if (phase == 0) {
            K = (job == 2) ? 98 : 9;
            src = (job == 0) ? h11 : (job == 1) ? c11 : h32;
            dst = (job == 0) ? h21t : (job == 1) ? c21p : h22t;
            if (tid < K)
                cs[tid] = (job == 2) ? fre23[(long)m * 98 + tid]
                                     : w12[(long)tid * 34 + m];
        } else {
            K = 34;
            src = (job == 0) ? h21 : (job == 1) ? c21 : h22;
            dst = (job == 0) ? h31t : (job == 1) ? c31p : h12t;
            if (tid < K)
                cs[tid] = (job == 2) ? fre12[(long)m * 34 + tid]
                                     : w23[(long)tid * 98 + m];
        }
        __syncthreads();
        float a0 = 0;
        for (int k = ks; k < K; k += 4) a0 += cs[k] * src[(long)k * 256 + n];
        red[tid] = a0;
        __syncthreads();
        if (ks == 0)
            dst[(long)m * 256 + n] = red[nl] + red[64 + nl] + red[128 + nl] + red[192 + nl];
    } else {
        const float* row = (phase == 0) ? h32 + m * 256 : h22 + m * 256;
        const float* pre = (phase == 0) ? wv2f : wv1f;
        const float* cm  = (phase == 0) ? c32 : c22;
        float* dst       = (phase == 0) ? fcb : fc2b;
        cs[tid] = row[tid];
        __syncthreads();
        float a0 = 0, a1 = 0, a2 = 0, a3 = 0;
        for (int k = ks; k + 12 < 256; k += 16) {
            long o = (long)k * 256 + n;
            a0 += cs[k] * uf2_W[o];        a1 += cs[k + 4] * uf2_W[o + 1024];
            a2 += cs[k + 8] * uf2_W[o + 2048]; a3 += cs[k + 12] * uf2_W[o + 3072];
        }
        red[tid] = a0 + a1 + a2 + a3;
        __syncthreads();
        if (ks == 0) {
            float tot = red[nl] + red[64 + nl] + red[128 + nl] + red[192 + nl]
                      + pre[(long)m * 256 + n] + wf2_b[n];
            dst[(long)m * 256 + n] = sigf(tot) * cm[(long)m * 256 + n];
        }
    }
}

// lstm_fused: fused gate matmuls + elementwise (see round-5 comments).
__global__ __launch_bounds__(256) void lstm_fused(int phase,
    const float* __restrict__ G,
    const float* __restrict__ h21t, const float* __restrict__ c21p,
    const float* __restrict__ h22t, const float* __restrict__ fcb,
    const float* __restrict__ h31t, const float* __restrict__ c31p,
    const float* __restrict__ h12t, const float* __restrict__ fc2b,
    const float* __restrict__ w23, const float* __restrict__ w12,
    const float* __restrict__ ui1, const float* __restrict__ uf1,
    const float* __restrict__ uo1, const float* __restrict__ uu1,
    const float* __restrict__ ui2, const float* __restrict__ uo2,
    const float* __restrict__ uu2,
    float* __restrict__ h21, float* __restrict__ c21,
    float* __restrict__ h22, float* __restrict__ c22,
    float* __restrict__ h31, float* __restrict__ h12)
{
    __shared__ float hs[256];
    __shared__ float cs[128];
    __shared__ float red[1024];
    const int x = blockIdx.x, y = blockIdx.y;
    const int tid = threadIdx.x, nl = tid & 63, ks = tid >> 6, n = x * 64 + nl;
    bool modef; int m, grow, Kx = 0;
    const float *hrow, *U0, *U1, *U2, *U3 = nullptr, *Sx = nullptr, *cmod = nullptr;
    float *ho, *co = nullptr;
    if (phase == 0) {
        if (y < 34) { modef = true;  m = y;      grow = 9 + m;  hrow = h21t;
                      U0 = ui1; U1 = uf1; U2 = uo1; U3 = uu1; cmod = c21p; ho = h21; co = c21; }
        else        { modef = false; m = y - 34; grow = 9 + m;  hrow = h22t;
                      U0 = ui2; U1 = uo2; U2 = uu2; Sx = fcb; Kx = 98; ho = h22; co = c22;
                      if (tid < 98) cs[tid] = w23[(long)m * 98 + tid]; }
    } else {
        if (y < 98) { modef = true;  m = y;      grow = 43 + m; hrow = h31t;
                      U0 = ui1; U1 = uf1; U2 = uo1; U3 = uu1; cmod = c31p; ho = h31; co = nullptr; }
        else        { modef = false; m = y - 98; grow = m;      hrow = h12t;
                      U0 = ui2; U1 = uo2; U2 = uu2; Sx = fc2b; Kx = 34; ho = h12; co = nullptr;
                      if (tid < 34) cs[tid] = w12[(long)m * 34 + tid]; }
    }
    hs[tid] = hrow[(long)m * 256 + tid];
    __syncthreads();
    float a0 = 0, a1 = 0, a2 = 0, a3 = 0;
    if (modef) {
        for (int k = ks; k < 256; k += 4) {
            float xv = hs[k]; long o = (long)k * 256 + n;
            a0 += xv * U0[o]; a1 += xv * U1[o]; a2 += xv * U2[o]; a3 += xv * U3[o];
        }
    } else {
        for (int k = ks; k < 256; k += 4) {
            float xv = hs[k]; long o = (long)k * 256 + n;
            a0 += xv * U0[o]; a1 += xv * U1[o]; a2 += xv * U2[o];
        }
        for (int k = ks; k < Kx; k += 4) a3 += cs[k] * Sx[(long)k * 256 + n];
    }
    red[tid] = a0; red[256 + tid] = a1; red[512 + tid] = a2; red[768 + tid] = a3;
    __syncthreads();
    if (ks == 0) {
        float t0 = 0, t1 = 0, t2 = 0, t3 = 0;
        #pragma unroll
        for (int s2 = 0; s2 < 4; s2++) {
            t0 += red[s2 * 64 + nl];       t1 += red[256 + s2 * 64 + nl];
            t2 += red[512 + s2 * 64 + nl]; t3 += red[768 + s2 * 64 + nl];
        }
        if (modef) {
            float ti = t0 + G[(0L * 141 + grow) * 256 + n];
            float tf = t1 + G[(1L * 141 + grow) * 256 + n];
            float to = t2 + G[(2L * 141 + grow) * 256 + n];
            float tu = t3 + G[(3L * 141 + grow) * 256 + n];
            float cv = sigf(ti) * tanhf(tu) + sigf(tf) * cmod[(long)m * 256 + n];
            ho[(long)m * 256 + n] = sigf(to) * tanhf(cv);
            if (co) co[(long)m * 256 + n] = cv;
        } else {
            float ti = t0 + G[(4L * 141 + grow) * 256 + n];
            float to = t1 + G[(5L * 141 + grow) * 256 + n];
            float tu = t2 + G[(6L * 141 + grow) * 256 + n];
            float cv = sigf(ti) * tanhf(tu) + t3;
            ho[(long)m * 256 + n] = sigf(to) * tanhf(cv);
            if (co) co[(long)m * 256 + n] = cv;
        }
    }
}

// le_h[l] = fp16( [h?1(l) | h?2(l) | tmpP(l)] @ mix_W + mix_b ). grid (4,141)
__global__ __launch_bounds__(256) void mix_mm(
    const float* __restrict__ h11, const float* __restrict__ h12,
    const float* __restrict__ h21, const float* __restrict__ h22,
    const float* __restrict__ h31, const float* __restrict__ h32,
    const float* __restrict__ tmpP, const float* __restrict__ mix_W,
    const float* __restrict__ mix_b, unsigned short* __restrict__ le_h)
{
    __shared__ float ls[768];
    __shared__ float red[256];
    const int x = blockIdx.x, l = blockIdx.y;
    const int tid = threadIdx.x, nl = tid & 63, ks = tid >> 6, n = x * 64 + nl;
    const float *pa, *pb; int r;
    if (l < 9)       { pa = h11; pb = h12; r = l; }
    else if (l < 43) { pa = h21; pb = h22; r = l - 9; }
    else             { pa = h31; pb = h32; r = l - 43; }
    for (int j = tid; j < 768; j += 256) {
        float v;
        if (j < 256)      v = pa[r * 256 + j];
        else if (j < 512) v = pb[r * 256 + (j - 256)];
        else              v = tmpP[l * 256 + (j - 512)];
        ls[j] = v;
    }
    __syncthreads();
    float a0 = 0, a1 = 0, a2 = 0, a3 = 0;
    for (int k = ks; k + 12 < 768; k += 16) {
        long o = (long)k * 256 + n;
        a0 += ls[k] * mix_W[o];        a1 += ls[k + 4] * mix_W[o + 1024];
        a2 += ls[k + 8] * mix_W[o + 2048]; a3 += ls[k + 12] * mix_W[o + 3072];
    }
    red[tid] = a0 + a1 + a2 + a3;
    __syncthreads();
    if (ks == 0) {
        float tot = red[nl] + red[64 + nl] + red[128 + nl] + red[192 + nl] + mix_b[n];
        le_h[(long)l * 256 + n] = f2h(tot);
    }
}

// Row softmax over S=512; fp32 in, fp16 out.
__global__ __launch_bounds__(256) void softmax512(
    const float* __restrict__ att, unsigned short* __restrict__ atth)
{
    __shared__ float red[256];
    const float* row = att + (long)blockIdx.x * 512;
    unsigned short* orow = atth + (long)blockIdx.x * 512;
    int t = threadIdx.x;
    float a = row[t], b = row[t + 256];
    red[t] = fmaxf(a, b);
    __syncthreads();
    for (int s = 128; s > 0; s >>= 1) {
        if (t < s) red[t] = fmaxf(red[t], red[t + s]);
        __syncthreads();
    }
    float m = red[0];
    __syncthreads();
    float ea = __expf(a - m), eb = __expf(b - m);
    red[t] = ea + eb;
    __syncthreads();
    for (int s = 128; s > 0; s >>= 1) {
        if (t < s) red[t] += red[t + s];
        __syncthreads();
    }
    float inv = 1.f / red[0];
    orow[t] = f2h(ea * inv);
    orow[t + 256] = f2h(eb * inv);
}

// out = sigmoid(bias + sum of nz partial K-slices)
__global__ __launch_bounds__(256) void out_final(
    const float* __restrict__ acc, const float* __restrict__ ob,
    float* __restrict__ out, int total, int nz)
{
    int i = blockIdx.x * 256 + threadIdx.x;
    if (i >= total) return;
    float v = ob[i % L];
    #pragma unroll 4
    for (int z = 0; z < nz; z++) v += acc[(long)z * total + i];
    out[i] = sigf(v);
}

extern "C" void kernel_launch(void* const* d_in, const int* in_sizes, int n_in,
                              void* d_out, int out_size, void* d_ws, size_t ws_size,
                              hipStream_t stream)
{
    (void)in_sizes; (void)n_in; (void)out_size; (void)ws_size;
    const int*   inputs      = (const int*)d_in[0];
    const float* text_hidden = (const float*)d_in[1];
    const float* label_enc   = (const float*)d_in[2];
    const float* w12   = (const float*)d_in[3];
    const float* w23   = (const float*)d_in[4];
    const float* fre12 = (const float*)d_in[5];
    const float* fre23 = (const float*)d_in[6];
    const float* wi1_W = (const float*)d_in[7],  *wi1_b = (const float*)d_in[8];
    const float* wf1_W = (const float*)d_in[9],  *wf1_b = (const float*)d_in[10];
    const float* wo1_W = (const float*)d_in[11], *wo1_b = (const float*)d_in[12];
    const float* wu1_W = (const float*)d_in[13], *wu1_b = (const float*)d_in[14];
    const float* wi2_W = (const float*)d_in[15], *wi2_b = (const float*)d_in[16];
    const float* wf2_W = (const float*)d_in[17], *wf2_b = (const float*)d_in[18];
    const float* wo2_W = (const float*)d_in[19], *wo2_b = (const float*)d_in[20];
    const float* wu2_W = (const float*)d_in[21], *wu2_b = (const float*)d_in[22];
    const float* ui1_W = (const float*)d_in[23], *uf1_W = (const float*)d_in[24];
    const float* uo1_W = (const float*)d_in[25], *uu1_W = (const float*)d_in[26];
    const float* ui2_W = (const float*)d_in[27], *uf2_W = (const float*)d_in[28];
    const float* uo2_W = (const float*)d_in[29], *uu2_W = (const float*)d_in[30];
    const float* mix_W = (const float*)d_in[31], *mix_b = (const float*)d_in[32];
    const float* tt_W  = (const float*)d_in[33], *tt_b  = (const float*)d_in[34];
    const float* Amat  = (const float*)d_in[35], *Wp    = (const float*)d_in[36];
    const float* out_W = (const float*)d_in[37], *out_b = (const float*)d_in[38];
    float* out = (float*)d_out;

    // ---- workspace (float units) ----
    // Aliased region: th16 = fp16 text_hidden (B*S*768 shorts = 12,582,912
    // floats = 50.3 MB), dead after the text GEMM (step 3). It overlays
    // [att | outacc | feat_h | att_h | out_Wh | G] (12,155,328 floats), ALL of
    // which are first written at step >= 4. Region = max(both) floats.
    float* ws = (float*)d_ws;
    float* region = ws;
    float* att    = region;                                        // B*L*S f32
    float* outacc = att + (long)B * L * S;                         // B*L*141 f32
    unsigned short* feat_h = (unsigned short*)(outacc + (long)B * L * 141); // B*L*H f16
    unsigned short* att_h  = feat_h + (long)B * L * H;             // B*L*S f16
    unsigned short* out_Wh = att_h + (long)B * L * S;              // L*36096 f16
    float* G = (float*)(out_Wh + (long)L * 36096);                 // 7*141*256 f32
    unsigned short* th16 = (unsigned short*)region;                // overlay
    {
        long memberFloats = (long)B * L * S + (long)B * L * 141
                          + (long)B * L * H / 2 + (long)B * L * S / 2
                          + (long)L * 36096 / 2 + 7L * 141 * 256;
        long th16Floats = (long)B * S * 768 / 2;
        ws += (memberFloats > th16Floats ? memberFloats : th16Floats) + 16;
    }
    unsigned short* text_h  = (unsigned short*)ws; ws += (long)B * S * H / 2;  // [b*s][h]
    unsigned short* text_hT = (unsigned short*)ws; ws += (long)B * S * H / 2;  // [b][h][s]
    unsigned short* tt_Wt   = (unsigned short*)ws; ws += 768 * H / 2;
    unsigned short* le_h    = (unsigned short*)ws; ws += L * H / 2 + 4;
    float* tmpP = ws; ws += L * H;
    float* wv2f = ws; ws += N3 * H;
    float* wv1f = ws; ws += N2 * H;
    float* h11  = ws; ws += N1 * H;  float* c11  = ws; ws += N1 * H;
    float* h21  = ws; ws += N2 * H;  float* c21  = ws; ws += N2 * H;
    float* h21t = ws; ws += N2 * H;  float* c21p = ws; ws += N2 * H;
    float* h31  = ws; ws += N3 * H;  float* h31t = ws; ws += N3 * H;
    float* c31p = ws; ws += N3 * H;
    float* h32  = ws; ws += N3 * H;  float* c32  = ws; ws += N3 * H;
    float* h22  = ws; ws += N2 * H;  float* c22  = ws; ws += N2 * H;
    float* h22t = ws; ws += N2 * H;  float* fcb  = ws; ws += N3 * H;
    float* h12  = ws; ws += N1 * H;  float* h12t = ws; ws += N1 * H;
    float* fc2b = ws; ws += N2 * H;

    // 1. text_hidden fp32 -> fp16 (streaming, HBM-bound)
    conv_h8<<<(int)(((long)B * S * 768 / 8 + 255) / 256), 256, 0, stream>>>(
        text_hidden, th16, (long)B * S * 768 / 8);
    // 2. tt_W (768x256) -> fp16 [256][768]
    transp_t64<<<dim3(768 / 64, 256 / 64), 256, 0, stream>>>(tt_W, tt_Wt, 768, 256);
    // 3. text = tanh(th16 @ tt_W + b) -> fp16 both layouts. th16 dead after.
    gemm_mfma<1, 2, 64><<<dim3(H / 128, (B * S) / 64, 1), 256, 0, stream>>>(
        th16, 768, 0, tt_Wt, 768, 0, nullptr, H, 0,
        B * S, H, 768, tt_b, nullptr, text_h, text_hT, 0);
    // 4. gate pre-activations G[7][141][256] (G in region: th16 now dead)
    gate_pre<<<dim3(28, 141), 256, 0, stream>>>(label_enc,
        wi1_W, wf1_W, wo1_W, wu1_W, wi2_W, wo2_W, wu2_W,
        wi1_b, wf1_b, wo1_b, wu1_b, wi2_b, wo2_b, wu2_b, G);
    // 5. independent two-stage rows: tmpP, wv2f, wv1f
    pre2<<<dim3(4, 273), 256, 0, stream>>>(Amat, label_enc, w23, w12, Wp, wf2_W,
        tmpP, wv2f, wv1f);
    // 6. out_W (36096x141) -> fp16 [141][36096]
    transp_t64<<<dim3(36096 / 64, 3), 256, 0, stream>>>(out_W, out_Wh, 36096, 141);
    // 7-12. label chain
    ew1<<<107, 256, 0, stream>>>(G, h11, c11, h32, c32);
    chain_mm<<<dim3(4, 200), 256, 0, stream>>>(0, w12, w23, fre23, fre12,
        h11, c11, h32, h21, c21, h22, wv2f, wv1f, wf2_b, uf2_W, c32, c22,
        h21t, c21p, h22t, fcb, h31t, c31p, h12t, fc2b);
    lstm_fused<<<dim3(4, 68), 256, 0, stream>>>(0, G,
        h21t, c21p, h22t, fcb, h31t, c31p, h12t, fc2b, w23, w12,
        ui1_W, uf1_W, uo1_W, uu1_W, ui2_W, uo2_W, uu2_W,
        h21, c21, h22, c22, h31, h12);
    chain_mm<<<dim3(4, 239), 256, 0, stream>>>(1, w12, w23, fre23, fre12,
        h11, c11, h32, h21, c21, h22, wv2f, wv1f, wf2_b, uf2_W, c32, c22,
        h21t, c21p, h22t, fcb, h31t, c31p, h12t, fc2b);
    lstm_fused<<<dim3(4, 107), 256, 0, stream>>>(1, G,
        h21t, c21p, h22t, fcb, h31t, c31p, h12t, fc2b, w23, w12,
        ui1_W, uf1_W, uo1_W, uu1_W, ui2_W, uo2_W, uu2_W,
        h21, c21, h22, c22, h31, h12);
    mix_mm<<<dim3(4, 141), 256, 0, stream>>>(h11, h12, h21, h22, h31, h32,
        tmpP, mix_W, mix_b, le_h);
    // 13. logits (+pad mask) fp32
    gemm_mfma<2, 2, 64><<<dim3(S / 128, (L + 63) / 64, B), 256, 0, stream>>>(
        le_h, H, 0, text_h, H, (long)S * H, att, S, (long)L * S,
        L, S, H, nullptr, inputs, nullptr, nullptr, 0);
    // 14. softmax -> fp16
    softmax512<<<B * L, 256, 0, stream>>>(att, att_h);
    // 15. feat (fp16 out, [b][l*256+h])
    gemm_mfma<3, 2, 64><<<dim3(H / 128, (L + 63) / 64, B), 256, 0, stream>>>(
        att_h, S, (long)L * S, text_hT, S, (long)H * S, nullptr, H, (long)L * H,
        L, H, S, nullptr, nullptr, feat_h, nullptr, 0);
    // 16. out-head: K-split MFMA -> 141 partial slices
    gemm_mfma<4, 2, 64><<<dim3(2, 1, 141), 256, 0, stream>>>(
        feat_h, L * H, 0, out_Wh, L * H, 0, outacc, L, (long)B * L,
        B, L, L * H, nullptr, nullptr, nullptr, nullptr, 256);
    // 17. reduce + sigmoid + bias
    out_final<<<(B * L + 255) / 256, 256, 0, stream>>>(outacc, out_b, out, B * L, 141);
}